// Round 1
// baseline (112.731 us; speedup 1.0000x reference)
//
#include <hip/hip_runtime.h>

typedef __attribute__((ext_vector_type(4))) float f32x4;
typedef __attribute__((ext_vector_type(8))) short bf16x8;

static __device__ __forceinline__ unsigned short f2bf(float f) {
    union { float f; unsigned int u; } v; v.f = f;
    unsigned int u = v.u;
    u += 0x7fffu + ((u >> 16) & 1u);   // round-to-nearest-even
    return (unsigned short)(u >> 16);
}

// Load 8 consecutive fp32 and convert to an MFMA bf16x8 A/B fragment register.
static __device__ __forceinline__ bf16x8 ld_cvt8(const float* __restrict__ p) {
    float4 f0 = *reinterpret_cast<const float4*>(p);
    float4 f1 = *reinterpret_cast<const float4*>(p + 4);
    union { unsigned short u[8]; bf16x8 v; } o;
    o.u[0] = f2bf(f0.x); o.u[1] = f2bf(f0.y);
    o.u[2] = f2bf(f0.z); o.u[3] = f2bf(f0.w);
    o.u[4] = f2bf(f1.x); o.u[5] = f2bf(f1.y);
    o.u[6] = f2bf(f1.z); o.u[7] = f2bf(f1.w);
    return o.v;
}

// prep: permute ONLY adj + W into MFMA fragment-order bf16 buffers (tiny: 1.9 MB
// traffic). x is consumed directly by `fused` — no 48 MB round-trip through HBM.
// Fragment chunk = 16 (m|n) x 32 (k) tile stored as [lane][8] bf16 (1 KB),
// lane = ((k&31)>>3)*16 + (m&15), elem jj = k&7.
//   adjfrag chunk = k0g*32 + m0              (512 chunks)
//   wtfrag  chunk = k0g*16 + n0   (Wt[n][k]=W[k][n], 128 chunks)
__global__ __launch_bounds__(256) void prep(
    const float* __restrict__ adj, const float* __restrict__ W,
    unsigned short* __restrict__ af, unsigned short* __restrict__ wf)
{
    const int wave = threadIdx.x >> 6, lane = threadIdx.x & 63;
    const int l15 = lane & 15, quad = lane >> 4;
    const int c = blockIdx.x * 4 + wave;     // 0..639, wave-uniform

    float t[8];
    unsigned short* dst;
    if (c < 512) {
        int k0g = c >> 5, m0 = c & 31;
        const float* src = adj + ((size_t)(m0 * 16 + l15)) * 512 + k0g * 32 + quad * 8;
        float4 f0 = *reinterpret_cast<const float4*>(src);
        float4 f1 = *reinterpret_cast<const float4*>(src + 4);
        t[0]=f0.x; t[1]=f0.y; t[2]=f0.z; t[3]=f0.w;
        t[4]=f1.x; t[5]=f1.y; t[6]=f1.z; t[7]=f1.w;
        dst = af + (size_t)c * 512 + lane * 8;
    } else {
        int c3 = c - 512, k0g = c3 >> 4, n0 = c3 & 15;
        int k = k0g * 32 + quad * 8, n = n0 * 16 + l15;
#pragma unroll
        for (int jj = 0; jj < 8; jj++) t[jj] = W[(size_t)(k + jj) * 256 + n];
        dst = wf + (size_t)c3 * 512 + lane * 8;
    }
    union { unsigned short u[8]; uint4 q; } o;
#pragma unroll
    for (int jj = 0; jj < 8; jj++) o.u[jj] = f2bf(t[jj]);
    *reinterpret_cast<uint4*>(dst) = o.q;
}

// Fused: block = (batch b, 64-col d-slice dq), 512 threads (8 waves).
// Each wave owns 64 rows x 64 cols -> 4x4 MFMA tile.
// Phase 1: h[j][64 d] = x_b @ W[:,slice] -> LDS (exact phase-2 B-frag order).
//   A-fragments of x are loaded DIRECTLY from the fp32 source (2x float4 per
//   fragment, rows contiguous across l15) + in-register f2bf convert. The 4
//   dq-blocks of batch b are (b, b+64, b+128, b+192) == b (mod 8) -> same XCD,
//   so the 4x re-read of x_b is L2-absorbed; HBM x traffic stays ~32 MB.
// Phase 2: out_b[:, slice] = adj @ h.  No barriers inside K-loops.
__global__ __launch_bounds__(512, 2) void fused(
    const float* __restrict__ x,
    const unsigned short* __restrict__ wf,
    const unsigned short* __restrict__ af,
    float* __restrict__ out)
{
    // ht[k0g(16)][ni(4)][lane(64)][8] bf16 = 64 KiB
    __shared__ __align__(16) unsigned short ht[32768];

    const int tid  = threadIdx.x;
    const int lane = tid & 63, wave = tid >> 6;   // wave 0..7
    const int l15  = lane & 15, quad = lane >> 4;
    const int b    = blockIdx.x;   // 0..63 (fast -> same-batch blocks share an XCD)
    const int dq   = blockIdx.y;   // 0..3

    // Per-lane base pointers.
    //   x:  row = b*512 + wave*64 + mi*16 + l15, col = k*32 + quad*8 .. +8
    //   wf: k0g step 16*64*8 = 8192 elems, ni step 512 elems
    //   af: k0g step 32*64*8 = 16384 elems, mi step 512 elems
    const float* xbase = x + ((size_t)(b * 512 + wave * 64 + l15)) * 256 + quad * 8;
    const unsigned short* wfp = wf + ((size_t)(dq * 4)) * 512 + lane * 8;
    const unsigned short* afp = af + ((size_t)(wave * 4)) * 512 + lane * 8;

    // ---------------- Phase 1: K=256, 8 k-steps; wave owns 64 j-rows ----------------
    f32x4 acc[4][4];
#pragma unroll
    for (int mi = 0; mi < 4; mi++)
#pragma unroll
        for (int ni = 0; ni < 4; ni++) acc[mi][ni] = (f32x4){0.f,0.f,0.f,0.f};

#pragma unroll
    for (int k = 0; k < 8; k++) {
        bf16x8 bw[4], a[4];
#pragma unroll
        for (int ni = 0; ni < 4; ni++)
            bw[ni] = *reinterpret_cast<const bf16x8*>(
                wfp + (size_t)k * 8192 + ni * 512);
#pragma unroll
        for (int mi = 0; mi < 4; mi++)
            a[mi] = ld_cvt8(xbase + (size_t)mi * 16 * 256 + k * 32);
#pragma unroll
        for (int mi = 0; mi < 4; mi++)
#pragma unroll
            for (int ni = 0; ni < 4; ni++)
                acc[mi][ni] = __builtin_amdgcn_mfma_f32_16x16x32_bf16(
                    a[mi], bw[ni], acc[mi][ni], 0, 0, 0);
    }

    // Epilogue: C-layout (j = wave*64 + mi*16 + quad*4 + r, dl = ni*16 + l15) ->
    // B-frag storage: k0g2 = wave*2 + (mi>>1), lane' = ((mi&1)*2+(quad>>1))*16 + l15,
    // elem = (quad&1)*4 + r  (r contiguous -> 8 B ds_write, conflict-free).
#pragma unroll
    for (int mi = 0; mi < 4; mi++) {
        int k0g2  = wave * 2 + (mi >> 1);
        int quadp = (mi & 1) * 2 + (quad >> 1);
#pragma unroll
        for (int ni = 0; ni < 4; ni++) {
            ushort4 p;
            p.x = f2bf(acc[mi][ni][0]); p.y = f2bf(acc[mi][ni][1]);
            p.z = f2bf(acc[mi][ni][2]); p.w = f2bf(acc[mi][ni][3]);
            *reinterpret_cast<ushort4*>(
                ht + ((k0g2 * 4 + ni) * 64 + quadp * 16 + l15) * 8
                   + (quad & 1) * 4) = p;
        }
    }
    __syncthreads();

    // ---------------- Phase 2: K=512, 16 k-steps; wave owns 64 out-rows ----------------
    f32x4 o[4][4];
#pragma unroll
    for (int mi = 0; mi < 4; mi++)
#pragma unroll
        for (int ni = 0; ni < 4; ni++) o[mi][ni] = (f32x4){0.f,0.f,0.f,0.f};

#pragma unroll
    for (int k = 0; k < 16; k++) {
        bf16x8 a2[4], hb[4];
#pragma unroll
        for (int mi = 0; mi < 4; mi++)
            a2[mi] = *reinterpret_cast<const bf16x8*>(
                afp + (size_t)k * 16384 + mi * 512);
#pragma unroll
        for (int ni = 0; ni < 4; ni++)
            hb[ni] = *reinterpret_cast<const bf16x8*>(
                ht + ((k * 4 + ni) * 64 + lane) * 8);
#pragma unroll
        for (int mi = 0; mi < 4; mi++)
#pragma unroll
            for (int ni = 0; ni < 4; ni++)
                o[mi][ni] = __builtin_amdgcn_mfma_f32_16x16x32_bf16(
                    a2[mi], hb[ni], o[mi][ni], 0, 0, 0);
    }

    // Store out fp32: row i = wave*64 + mi*16 + quad*4 + r, col dq*64 + ni*16 + l15
    float* ob = out + ((size_t)b * 512) * 256 + dq * 64;
#pragma unroll
    for (int mi = 0; mi < 4; mi++) {
        int i0 = wave * 64 + mi * 16 + quad * 4;
#pragma unroll
        for (int ni = 0; ni < 4; ni++) {
            int d = ni * 16 + l15;
#pragma unroll
            for (int r = 0; r < 4; r++)
                ob[(size_t)(i0 + r) * 256 + d] = o[mi][ni][r];
        }
    }
}

extern "C" void kernel_launch(void* const* d_in, const int* in_sizes, int n_in,
                              void* d_out, int out_size, void* d_ws, size_t ws_size,
                              hipStream_t stream) {
    const float* x   = (const float*)d_in[0];
    // d_in[1] = batch ids (unused; block-contiguous layout by construction)
    const float* W   = (const float*)d_in[2];
    const float* Adj = (const float*)d_in[3];
    float* out = (float*)d_out;

    unsigned short* afrag = (unsigned short*)d_ws;    // 262144 elems (512 KB)
    unsigned short* wfrag = afrag + 262144;           // 65536 elems (128 KB)

    prep<<<160, 256, 0, stream>>>(Adj, W, afrag, wfrag);
    fused<<<dim3(64, 4), 512, 0, stream>>>(x, wfrag, afrag, out);
}